// Round 9
// baseline (1704.018 us; speedup 1.0000x reference)
//
#include <hip/hip_runtime.h>
#include <hip/hip_bf16.h>

// MPNN, round 9: persistent-ish step kernel. 512 blocks x 512 thr (2 blk/CU),
// B staged in LDS once per block; each wave independently processes 3-4
// 16-row groups (12500 groups total), software-pipelined: nbr prefetched one
// group ahead, A fragments double-buffered so gathers overlap MFMA.
//
// Folded math (verified r4-r8): per step
//   h' = relu([hv | hg | e] @ B + btot),  B rows: U1 ; Vw@U2 ; Ew@U3
//   readout fm = sum_nodes relu(h @ (Rw[:70]+Rw[70:]) + Rb); then tiny MLP.
// K padded to 224 (0-pad B rows kill fragment-tail garbage), N padded to 80.
// h state bf16, stride 72 (144 B rows).

#define NNODES 200000
#define DEG 16
#define NGRP 12500           // 200000/16 exactly
#define NWAVES 4096          // 512 blocks x 8 waves

typedef __attribute__((ext_vector_type(8))) short short8;
typedef __attribute__((ext_vector_type(4))) float f32x4;

__device__ __forceinline__ unsigned short f2bf(float f) {
    unsigned u = __float_as_uint(f);
    unsigned r = 0x7FFFu + ((u >> 16) & 1u);
    return (unsigned short)((u + r) >> 16);
}

// map padded k (0..223) -> Bstep row (0..145) or -1
__device__ __forceinline__ int kmap(int k) {
    if (k < 70) return k;                       // hv
    if (k >= 96 && k < 166) return k - 26;      // hg -> rows 70..139
    if (k >= 192 && k < 198) return k - 52;     // e  -> rows 140..145
    return -1;
}

// ---------------- prepA: folds + bias + readout fragments (96 blocks) ----------------
__global__ void prepA_kernel(const float* __restrict__ Vw, const float* __restrict__ Vb,
                             const float* __restrict__ Ew, const float* __restrict__ Eb,
                             const float* __restrict__ Uw, const float* __restrict__ Ub,
                             const float* __restrict__ Rw,
                             float* __restrict__ Bstep, float* __restrict__ bias80,
                             unsigned short* __restrict__ Rcg) {
    const int b = blockIdx.x, t = threadIdx.x;
    if (b < 70) {
        if (t < 70) {
            Bstep[b * 70 + t] = Uw[b * 70 + t];
            float s = 0.f;
            for (int c2 = 0; c2 < 70; ++c2) s += Vw[b * 70 + c2] * Uw[(70 + c2) * 70 + t];
            Bstep[(70 + b) * 70 + t] = s;
        }
    } else if (b == 70) {
        for (int i = t; i < 6 * 70; i += 256) {
            const int c = i / 70, n = i % 70;
            float s = 0.f;
            for (int c2 = 0; c2 < 6; ++c2) s += Ew[c * 6 + c2] * Uw[(140 + c2) * 70 + n];
            Bstep[(140 + c) * 70 + n] = s;
        }
    } else if (b == 71) {
        if (t < 80) {
            float s = 0.f;
            if (t < 70) {
                s = Ub[t];
                for (int c2 = 0; c2 < 70; ++c2) s += Vb[c2] * Uw[(70 + c2) * 70 + t];
                for (int c2 = 0; c2 < 6; ++c2) s += Eb[c2] * Uw[(140 + c2) * 70 + t];
            }
            bias80[t] = s;
        }
    } else {
        // readout fragments: f = kt*8+nt, 24 frags of 512 bf16
        const int f = b - 72;
        const int nt = f & 7, kt = f >> 3;
        for (int e = t; e < 512; e += 256) {
            const int l = e >> 3, jj = e & 7;
            const int col = nt * 16 + (l & 15);
            const int k = kt * 32 + (l >> 4) * 8 + jj;
            const float v = (k < 70) ? (Rw[k * 128 + col] + Rw[(70 + k) * 128 + col]) : 0.f;
            Rcg[f * 512 + e] = f2bf(v);
        }
    }
}

// ---------------- prepB: step-B fragments (35 blocks) ----------------
__global__ void prepB_kernel(const float* __restrict__ Bstep, unsigned short* __restrict__ Btg) {
    const int f = blockIdx.x, t = threadIdx.x;   // f = kt*5 + nt
    const int nt = f % 5, kt = f / 5;
    for (int e = t; e < 512; e += 256) {
        const int l = e >> 3, jj = e & 7;
        const int col = nt * 16 + (l & 15);
        const int k = kt * 32 + (l >> 4) * 8 + jj;
        const int kr = kmap(k);
        const float v = (col < 70 && kr >= 0) ? Bstep[kr * 70 + col] : 0.f;
        Btg[f * 512 + e] = f2bf(v);
    }
}

// ---------------- input conversions ----------------
__global__ void conv_h_kernel(const float* __restrict__ h0, unsigned short* __restrict__ hb) {
    const long total = (long)NNODES * 36;
    for (long i = (long)blockIdx.x * blockDim.x + threadIdx.x; i < total;
         i += (long)gridDim.x * blockDim.x) {
        const long node = i / 36;
        const int kp = (int)(i % 36);
        unsigned v = 0u;
        if (kp < 35) {
            const float* p = h0 + node * 70 + kp * 2;
            v = (unsigned)f2bf(p[0]) | ((unsigned)f2bf(p[1]) << 16);
        }
        ((unsigned*)(hb + node * 72))[kp] = v;
    }
}

__global__ void conv_e_kernel(const float* __restrict__ e, unsigned short* __restrict__ eb) {
    const long total = (long)NNODES * DEG * 4;
    for (long i = (long)blockIdx.x * blockDim.x + threadIdx.x; i < total;
         i += (long)gridDim.x * blockDim.x) {
        const long row = i / 4;
        const int c = (int)(i % 4);
        unsigned v = 0u;
        if (c < 3) {
            const float* p = e + row * 6 + c * 2;
            v = (unsigned)f2bf(p[0]) | ((unsigned)f2bf(p[1]) << 16);
        }
        ((unsigned*)(eb + row * 8))[c] = v;
    }
}

// ---------------- one message-passing step ----------------
__global__ __launch_bounds__(512, 4) void step_kernel(
    const unsigned short* __restrict__ hin, const unsigned short* __restrict__ edgeb,
    const int* __restrict__ nbr, const unsigned short* __restrict__ Btg,
    const float* __restrict__ bias80, unsigned short* __restrict__ hout, const int j) {
    __shared__ __align__(16) unsigned short Btb[35 * 512];  // 35 frags x 1KB
    __shared__ float bias_s[80];
    const int tid = threadIdx.x;

    {   // flat conflict-free staging: 2240 uint4
        const uint4* src = (const uint4*)Btg;
        uint4* dst = (uint4*)Btb;
        for (int i = tid; i < 2240; i += 512) dst[i] = src[i];
    }
    if (tid < 80) bias_s[tid] = bias80[tid];

    const int w = tid >> 6, l = tid & 63;
    const int lm = l & 15, lhi = l >> 4, lk = lhi * 8;
    const int lofs = l * 8;
    const int gw = blockIdx.x * 8 + w;   // wave id 0..4095

    auto loadA = [&](short8* a, long row, int g) {
        const unsigned short* hr = hin + row * 72;
        a[0] = *(const short8*)(hr + lk);
        a[1] = *(const short8*)(hr + 32 + lk);
        a[2] = *(const short8*)(hr + 64 + lk);     // tail overlap: B rows zero
        const unsigned short* gr = hin + (long)g * 72;
        a[3] = *(const short8*)(gr + lk);
        a[4] = *(const short8*)(gr + 32 + lk);
        a[5] = *(const short8*)(gr + 64 + lk);
        a[6] = *(const short8*)(edgeb + (row * DEG + j) * 8 + lk);
    };

    auto doGroup = [&](const short8* a, long grp) {
        f32x4 acc[5] = {{0.f, 0.f, 0.f, 0.f}, {0.f, 0.f, 0.f, 0.f}, {0.f, 0.f, 0.f, 0.f},
                        {0.f, 0.f, 0.f, 0.f}, {0.f, 0.f, 0.f, 0.f}};
#pragma unroll
        for (int kt = 0; kt < 7; ++kt) {
#pragma unroll
            for (int nt = 0; nt < 5; ++nt) {
                const short8 b = *(const short8*)&Btb[(kt * 5 + nt) * 512 + lofs];
                acc[nt] = __builtin_amdgcn_mfma_f32_16x16x32_bf16(a[kt], b, acc[nt], 0, 0, 0);
            }
        }
        // D: col = lane&15, row = (lane>>4)*4 + r (verified)
#pragma unroll
        for (int nt = 0; nt < 5; ++nt) {
            const int col = nt * 16 + lm;
            if (col < 70) {
                const float bias = bias_s[col];
#pragma unroll
                for (int r = 0; r < 4; ++r) {
                    const long node = grp * 16 + lhi * 4 + r;
                    hout[node * 72 + col] = f2bf(fmaxf(acc[nt][r] + bias, 0.f));
                }
            }
        }
    };

    // groups gw + 4096*i, i = 0..3 (12500 groups exactly cover 200000 nodes)
    const long r0 = (long)gw * 16 + lm;
    const int g0 = nbr[r0 * DEG + j];
    short8 A0[7], A1[7];
    loadA(A0, r0, g0);
    const long r1 = r0 + (long)NWAVES * 16;          // grp1 = gw+4096, always valid
    const int g1 = nbr[r1 * DEG + j];
    __syncthreads();   // B tile ready

    // iter 0
    loadA(A1, r1, g1);
    const int grp2 = gw + 2 * NWAVES;
    const bool v2 = grp2 < NGRP;
    const long r2 = r1 + (long)NWAVES * 16;
    int g2 = 0;
    if (v2) g2 = nbr[r2 * DEG + j];
    doGroup(A0, gw);

    // iter 1
    if (v2) loadA(A0, r2, g2);
    const int grp3 = gw + 3 * NWAVES;
    const bool v3 = grp3 < NGRP;
    const long r3 = r2 + (long)NWAVES * 16;
    int g3 = 0;
    if (v3) g3 = nbr[r3 * DEG + j];
    doGroup(A1, gw + NWAVES);

    // iter 2
    if (v3) loadA(A1, r3, g3);
    if (v2) doGroup(A0, grp2);

    // iter 3
    if (v3) doGroup(A1, grp3);
}

// ---------------- readout: fm[128] += sum relu(h @ Rc + Rb) ----------------
__global__ __launch_bounds__(512, 4) void readout_kernel(
    const unsigned short* __restrict__ hb, const unsigned short* __restrict__ Rcg,
    const float* __restrict__ Rb, float* __restrict__ fm) {
    __shared__ __align__(16) unsigned short Rs[24 * 512];
    __shared__ float Rb_s[128];
    __shared__ float red[8][128];
    const int tid = threadIdx.x;
    const long node0 = (long)blockIdx.x * 128;

    {
        const uint4* src = (const uint4*)Rcg;
        uint4* dst = (uint4*)Rs;
        for (int i = tid; i < 1536; i += 512) dst[i] = src[i];
    }
    if (tid < 128) Rb_s[tid] = Rb[tid];

    const int w = tid >> 6, l = tid & 63;
    const int lm = l & 15, lhi = l >> 4, lk = lhi * 8;
    const int lofs = l * 8;
    const long anode = node0 + w * 16 + lm;
    const long nl = anode < NNODES ? anode : (NNODES - 1);
    short8 a[3];
    {
        const unsigned short* hr = hb + nl * 72;
        a[0] = *(const short8*)(hr + lk);
        a[1] = *(const short8*)(hr + 32 + lk);
        a[2] = *(const short8*)(hr + 64 + lk);
    }
    __syncthreads();

    f32x4 acc[8] = {{0.f, 0.f, 0.f, 0.f}, {0.f, 0.f, 0.f, 0.f}, {0.f, 0.f, 0.f, 0.f},
                    {0.f, 0.f, 0.f, 0.f}, {0.f, 0.f, 0.f, 0.f}, {0.f, 0.f, 0.f, 0.f},
                    {0.f, 0.f, 0.f, 0.f}, {0.f, 0.f, 0.f, 0.f}};
#pragma unroll
    for (int kt = 0; kt < 3; ++kt) {
#pragma unroll
        for (int nt = 0; nt < 8; ++nt) {
            const short8 b = *(const short8*)&Rs[(kt * 8 + nt) * 512 + lofs];
            acc[nt] = __builtin_amdgcn_mfma_f32_16x16x32_bf16(a[kt], b, acc[nt], 0, 0, 0);
        }
    }
#pragma unroll
    for (int nt = 0; nt < 8; ++nt) {
        const int col = nt * 16 + lm;
        const float bias = Rb_s[col];
        float s = 0.f;
#pragma unroll
        for (int r = 0; r < 4; ++r) {
            const long dnode = node0 + w * 16 + lhi * 4 + r;
            if (dnode < NNODES) s += fmaxf(acc[nt][r] + bias, 0.f);
        }
        s += __shfl_xor(s, 16);
        s += __shfl_xor(s, 32);
        if (l < 16) red[w][col] = s;
    }
    __syncthreads();
    if (tid < 128) {
        float s = 0.f;
#pragma unroll
        for (int r = 0; r < 8; ++r) s += red[r][tid];
        atomicAdd(&fm[tid], s);
    }
}

// ---------------- tiny MLP tail ----------------
__global__ void mlp_kernel(const float* __restrict__ fm,
                           const float* __restrict__ S1w, const float* __restrict__ S1b,
                           const float* __restrict__ S2w, const float* __restrict__ S2b,
                           const float* __restrict__ Hw, const float* __restrict__ Hb,
                           const float* __restrict__ Ow, const float* __restrict__ Ob,
                           float* __restrict__ out) {
    __shared__ float fms[128], a_s[128], b_s[100], c_s[100];
    const int t = threadIdx.x;
    fms[t] = fm[t];
    __syncthreads();
    {
        float s = S1b[t];
        for (int c = 0; c < 128; ++c) s += fms[c] * S1w[c * 128 + t];
        a_s[t] = fmaxf(s, 0.f);
    }
    __syncthreads();
    if (t < 100) {
        float s = S2b[t];
        for (int c = 0; c < 128; ++c) s += a_s[c] * S2w[c * 100 + t];
        b_s[t] = s;  // no activation before hidden layer
    }
    __syncthreads();
    if (t < 100) {
        float s = Hb[t];
        for (int c = 0; c < 100; ++c) s += b_s[c] * Hw[c * 100 + t];
        c_s[t] = fmaxf(s, 0.f);
    }
    __syncthreads();
    if (t == 0) {
        float s = Ob[0];
        for (int c = 0; c < 100; ++c) s += c_s[c] * Ow[c];
        out[0] = s;
    }
}

extern "C" void kernel_launch(void* const* d_in, const int* in_sizes, int n_in,
                              void* d_out, int out_size, void* d_ws, size_t ws_size,
                              hipStream_t stream) {
    const float* h0   = (const float*)d_in[0];
    const float* edge = (const float*)d_in[1];
    const int*   nbr  = (const int*)d_in[2];
    const float* Vw = (const float*)d_in[3];
    const float* Vb = (const float*)d_in[4];
    const float* Ew = (const float*)d_in[5];
    const float* Eb = (const float*)d_in[6];
    const float* Uw = (const float*)d_in[7];
    const float* Ub = (const float*)d_in[8];
    const float* Rw = (const float*)d_in[9];
    const float* Rb = (const float*)d_in[10];
    const float* S1w = (const float*)d_in[11];
    const float* S1b = (const float*)d_in[12];
    const float* S2w = (const float*)d_in[13];
    const float* S2b = (const float*)d_in[14];
    const float* Hw = (const float*)d_in[15];
    const float* Hb = (const float*)d_in[16];
    const float* Ow = (const float*)d_in[17];
    const float* Ob = (const float*)d_in[18];
    float* out = (float*)d_out;

    // workspace layout (~108.9 MB, all offsets 16B-aligned)
    char* ws = (char*)d_ws;
    unsigned short* hA    = (unsigned short*)(ws);              // 200000*72 bf16 + pad
    unsigned short* hB    = (unsigned short*)(ws + 28801024);   // same
    unsigned short* edgeb = (unsigned short*)(ws + 57602048);   // 200000*16*8 bf16 + pad
    unsigned short* Btg   = (unsigned short*)(ws + 108803072);  // 35*512 bf16 frag blob
    unsigned short* Rcg   = (unsigned short*)(ws + 108838912);  // 24*512 bf16 frag blob
    float* bias80 = (float*)(ws + 108863488);                   // 80
    float* fm     = (float*)(ws + 108863808);                   // 128
    float* Bstep  = (float*)(ws + 108864320);                   // 146*70 fp32 scratch

    conv_h_kernel<<<2048, 256, 0, stream>>>(h0, hA);
    conv_e_kernel<<<2048, 256, 0, stream>>>(edge, edgeb);
    prepA_kernel<<<96, 256, 0, stream>>>(Vw, Vb, Ew, Eb, Uw, Ub, Rw, Bstep, bias80, Rcg);
    prepB_kernel<<<35, 256, 0, stream>>>(Bstep, Btg);
    hipMemsetAsync(fm, 0, 128 * sizeof(float), stream);

    const unsigned short* cur = hA;
    for (int s = 0; s < 48; ++s) {
        unsigned short* o = (s & 1) ? hA : hB;  // s=0 writes hB; s=47 writes hA
        step_kernel<<<512, 512, 0, stream>>>(cur, edgeb, nbr, Btg, bias80, o, s & 15);
        cur = o;
    }
    readout_kernel<<<(NNODES + 127) / 128, 512, 0, stream>>>(cur, Rcg, Rb, fm);
    mlp_kernel<<<1, 128, 0, stream>>>(fm, S1w, S1b, S2w, S2b, Hw, Hb, Ow, Ob, out);
}